// Round 2
// baseline (180.816 us; speedup 1.0000x reference)
//
#include <hip/hip_runtime.h>
#include <math.h>

// Problem constants
#define BB 32
#define PP 2048
#define DD 768
#define TT 3
#define OO 128
#define HH 192
#define CC 16              // chunks of P per batch for the streaming kernel
#define ROWS (PP / CC)     // 128 rows per block
#define SCALE 0.03608439182435161f  // 1/sqrt(768)

// ---------------------------------------------------------------------------
// K1a: q[t,e] = sum_d tt[t,d] * Wq[t,d,e] + bq[t,e]
// grid 36 = T*12 blocks (64 e's each), 256 threads: 4 d-groups of 192
// ---------------------------------------------------------------------------
__global__ void k_q(const float* __restrict__ tt, const float* __restrict__ Wq,
                    const float* __restrict__ bq, float* __restrict__ q) {
    __shared__ float red[4][64];
    int t = blockIdx.x / 12, ec = blockIdx.x % 12;
    int tid = threadIdx.x;
    int e = ec * 64 + (tid & 63);
    int dg = tid >> 6;
    const float* w  = Wq + (size_t)t * DD * DD + e;
    const float* tr = tt + t * DD;
    float acc = 0.f;
    for (int d = dg * 192; d < dg * 192 + 192; ++d)
        acc += tr[d] * w[(size_t)d * DD];
    red[dg][tid & 63] = acc;
    __syncthreads();
    if (dg == 0) {
        float s = red[0][tid] + red[1][tid] + red[2][tid] + red[3][tid] + bq[t * DD + e];
        q[t * DD + e] = s;
    }
}

// ---------------------------------------------------------------------------
// K1b: kq[t,d] = SCALE * sum_e Wk[t,d,e] * q[t,e]   (row-contiguous matvec)
// grid 576 = T*192, one wave per d (4 waves/block)
// ---------------------------------------------------------------------------
__global__ void k_kq(const float* __restrict__ Wk, const float* __restrict__ q,
                     float* __restrict__ kq) {
    int t = blockIdx.x / 192;
    int d = (blockIdx.x % 192) * 4 + (threadIdx.x >> 6);
    int L = threadIdx.x & 63;
    const float4* wr = (const float4*)(Wk + (size_t)(t * DD + d) * DD);
    const float4* qr = (const float4*)(q + t * DD);
    float s = 0.f;
#pragma unroll
    for (int g = 0; g < 3; ++g) {
        float4 a = wr[g * 64 + L], b = qr[g * 64 + L];
        s += a.x * b.x + a.y * b.y + a.z * b.z + a.w * b.w;
    }
#pragma unroll
    for (int off = 32; off; off >>= 1) s += __shfl_xor(s, off);
    if (L == 0) kq[t * DD + d] = s * SCALE;
}

// ---------------------------------------------------------------------------
// K2 main stream: per x-row (skip masked!): s[t] = x_row . kq[t];
//   e = exp(s); l[t] += e; xa_acc[t] += e * x_row.
// grid 512 = B*16 blocks, 256 threads (4 waves, 32 rows each).
// Outputs per-block partials: xap[bid][t*768+d], lp[bid][t].
// ---------------------------------------------------------------------------
__global__ __launch_bounds__(256, 2) void k_main(const float* __restrict__ x,
        const int* __restrict__ mask, const float* __restrict__ kq,
        float* __restrict__ xap, float* __restrict__ lp) {
    __shared__ float red[4][TT * DD];   // 36 KB
    __shared__ float redl[4][TT];
    int bid = blockIdx.x;
    int b = bid >> 4, c = bid & 15;
    int tid = threadIdx.x, w = tid >> 6, L = tid & 63;

    float4 kqr[TT][3];
#pragma unroll
    for (int t = 0; t < TT; ++t)
#pragma unroll
        for (int g = 0; g < 3; ++g)
            kqr[t][g] = *(const float4*)(kq + t * DD + g * 256 + 4 * L);

    float4 acc[TT][3] = {};
    float l[TT] = {0.f, 0.f, 0.f};
    const float* xb = x + (size_t)b * PP * DD;
    const int* mb = mask + b * PP;
    int p0 = c * ROWS + w * (ROWS / 4);

    for (int r = 0; r < ROWS / 4; ++r) {
        int p = p0 + r;
        if (mb[p]) continue;                       // masked rows contribute 0
        const float4* xr = (const float4*)(xb + (size_t)p * DD);
        float4 xv[3];
#pragma unroll
        for (int g = 0; g < 3; ++g) xv[g] = xr[g * 64 + L];
        float s[TT];
#pragma unroll
        for (int t = 0; t < TT; ++t) {
            float a = 0.f;
#pragma unroll
            for (int g = 0; g < 3; ++g)
                a += xv[g].x * kqr[t][g].x + xv[g].y * kqr[t][g].y
                   + xv[g].z * kqr[t][g].z + xv[g].w * kqr[t][g].w;
            s[t] = a;
        }
#pragma unroll
        for (int off = 32; off; off >>= 1) {
            s[0] += __shfl_xor(s[0], off);
            s[1] += __shfl_xor(s[1], off);
            s[2] += __shfl_xor(s[2], off);
        }
#pragma unroll
        for (int t = 0; t < TT; ++t) {
            float e = expf(s[t]);                  // scores are tiny; no max needed
            l[t] += e;
#pragma unroll
            for (int g = 0; g < 3; ++g) {
                acc[t][g].x += e * xv[g].x;
                acc[t][g].y += e * xv[g].y;
                acc[t][g].z += e * xv[g].z;
                acc[t][g].w += e * xv[g].w;
            }
        }
    }

#pragma unroll
    for (int t = 0; t < TT; ++t)
#pragma unroll
        for (int g = 0; g < 3; ++g)
            *(float4*)&red[w][t * DD + g * 256 + 4 * L] = acc[t][g];
    if (L == 0) {
#pragma unroll
        for (int t = 0; t < TT; ++t) redl[w][t] = l[t];
    }
    __syncthreads();

    float* outp = xap + (size_t)bid * (TT * DD);
#pragma unroll
    for (int k = 0; k < 9; ++k) {
        int i = tid + k * 256;
        outp[i] = red[0][i] + red[1][i] + red[2][i] + red[3][i];
    }
    if (tid < TT)
        lp[bid * TT + tid] = redl[0][tid] + redl[1][tid] + redl[2][tid] + redl[3][tid];
}

// ---------------------------------------------------------------------------
// K3: combine chunk partials:  xa[t,b,d] = (sum_c xap) / (sum_c lp)
// grid 96 = T*B blocks, 256 threads
// ---------------------------------------------------------------------------
__global__ void k_comb(const float* __restrict__ xap, const float* __restrict__ lp,
                       float* __restrict__ xa) {
    int t = blockIdx.x >> 5, b = blockIdx.x & 31;
    int tid = threadIdx.x;
    float lsum = 0.f;
#pragma unroll
    for (int c = 0; c < CC; ++c) lsum += lp[(b * CC + c) * TT + t];
    float inv = 1.0f / lsum;
#pragma unroll
    for (int k = 0; k < 3; ++k) {
        int d = tid + k * 256;
        float s = 0.f;
#pragma unroll
        for (int c = 0; c < CC; ++c)
            s += xap[(size_t)(b * CC + c) * (TT * DD) + t * DD + d];
        xa[(t * BB + b) * DD + d] = s * inv;
    }
}

// ---------------------------------------------------------------------------
// K4/K5: out[t,b,e] = in[t,b,:] . W[t,:,e] + bias[t,e] (+ tt[t,e])
// 512 threads: b = tid>>4 (0..31), e = nc*16 + (tid&15).  N=768: grid T*48.
// ---------------------------------------------------------------------------
template<bool ADD_TT>
__global__ void k_gemm768(const float* __restrict__ in, const float* __restrict__ W,
                          const float* __restrict__ bias, const float* __restrict__ tt,
                          float* __restrict__ out) {
    int t = blockIdx.x / 48, nc = blockIdx.x % 48;
    int tid = threadIdx.x;
    int b = tid >> 4, e = nc * 16 + (tid & 15);
    const float* inr = in + (size_t)(t * BB + b) * DD;
    const float* wc = W + (size_t)t * DD * DD + e;
    float acc = bias[t * DD + e];
    if (ADD_TT) acc += tt[t * DD + e];
#pragma unroll 8
    for (int d = 0; d < DD; ++d)
        acc += inr[d] * wc[(size_t)d * DD];
    out[(size_t)(t * BB + b) * DD + e] = acc;
}

// K6: h = gelu_exact(y2 @ h1w + h1b), N=192: grid T*12 = 36, 512 thr
__global__ void k_gemm_h(const float* __restrict__ y2, const float* __restrict__ h1w,
                         const float* __restrict__ h1b, float* __restrict__ h) {
    int t = blockIdx.x / 12, nc = blockIdx.x % 12;
    int tid = threadIdx.x;
    int b = tid >> 4, e = nc * 16 + (tid & 15);
    const float* inr = y2 + (size_t)(t * BB + b) * DD;
    const float* wc = h1w + (size_t)t * DD * HH + e;
    float acc = h1b[t * HH + e];
#pragma unroll 8
    for (int d = 0; d < DD; ++d)
        acc += inr[d] * wc[(size_t)d * HH];
    acc = 0.5f * acc * (1.0f + erff(acc * 0.70710678118654752f));
    h[(t * BB + b) * HH + e] = acc;
}

// K7: out = h @ h2w + h2b, N=128, K=192: grid T*8 = 24, 512 thr
__global__ void k_gemm_o(const float* __restrict__ h, const float* __restrict__ h2w,
                         const float* __restrict__ h2b, float* __restrict__ out) {
    int t = blockIdx.x / 8, nc = blockIdx.x % 8;
    int tid = threadIdx.x;
    int b = tid >> 4, e = nc * 16 + (tid & 15);
    const float* inr = h + (size_t)(t * BB + b) * HH;
    const float* wc = h2w + (size_t)t * HH * OO + e;
    float acc = h2b[t * OO + e];
#pragma unroll 8
    for (int d = 0; d < HH; ++d)
        acc += inr[d] * wc[(size_t)d * OO];
    out[(size_t)(t * BB + b) * OO + e] = acc;
}

// ---------------------------------------------------------------------------
extern "C" void kernel_launch(void* const* d_in, const int* in_sizes, int n_in,
                              void* d_out, int out_size, void* d_ws, size_t ws_size,
                              hipStream_t stream) {
    const float* x    = (const float*)d_in[0];
    const int*   mask = (const int*)d_in[1];   // True = masked
    const float* tt   = (const float*)d_in[2];
    const float* Wq   = (const float*)d_in[3];
    const float* bq   = (const float*)d_in[4];
    const float* Wk   = (const float*)d_in[5];
    // d_in[6] = bk: unused — adds a per-(t) constant to scores, cancels in softmax
    const float* Wv   = (const float*)d_in[7];
    const float* bv   = (const float*)d_in[8];
    const float* Wo   = (const float*)d_in[9];
    const float* bo   = (const float*)d_in[10];
    const float* h1w  = (const float*)d_in[11];
    const float* h1b  = (const float*)d_in[12];
    const float* h2w  = (const float*)d_in[13];
    const float* h2b  = (const float*)d_in[14];
    float* out = (float*)d_out;

    // workspace layout (floats); total ~5.7 MB
    float* ws  = (float*)d_ws;
    float* q   = ws;                       // T*D        = 2304
    float* kq  = q + TT * DD;              // T*D        = 2304
    float* xap = kq + TT * DD;             // 512*T*D    = 1,179,648
    float* lp  = xap + 512 * TT * DD;      // 512*T      = 1536
    float* xa  = lp + 512 * TT;            // T*B*D      = 73728
    float* y   = xa + TT * BB * DD;        // T*B*D
    float* y2  = y + TT * BB * DD;         // T*B*D
    float* h   = y2 + TT * BB * DD;        // T*B*H      = 18432

    hipLaunchKernelGGL(k_q,    dim3(36),  dim3(256), 0, stream, tt, Wq, bq, q);
    hipLaunchKernelGGL(k_kq,   dim3(576), dim3(256), 0, stream, Wk, q, kq);
    hipLaunchKernelGGL(k_main, dim3(512), dim3(256), 0, stream, x, mask, kq, xap, lp);
    hipLaunchKernelGGL(k_comb, dim3(96),  dim3(256), 0, stream, xap, lp, xa);
    hipLaunchKernelGGL((k_gemm768<false>), dim3(144), dim3(512), 0, stream, xa, Wv, bv, nullptr, y);
    hipLaunchKernelGGL((k_gemm768<true>),  dim3(144), dim3(512), 0, stream, y, Wo, bo, tt, y2);
    hipLaunchKernelGGL(k_gemm_h, dim3(36), dim3(512), 0, stream, y2, h1w, h1b, h);
    hipLaunchKernelGGL(k_gemm_o, dim3(24), dim3(512), 0, stream, h, h2w, h2b, out);
}

// Round 3
// 102.328 us; speedup vs baseline: 1.7670x; 1.7670x over previous
//
#include <hip/hip_runtime.h>
#include <math.h>

// Problem constants
#define BB 32
#define PP 2048
#define DD 768
#define TT 3
#define OO 128
#define HH 192
#define CC 32              // chunks of P per batch for the streaming kernel
#define ROWS (PP / CC)     // 64 rows per block
#define SCALE 0.03608439182435161f  // 1/sqrt(768)

// ---------------------------------------------------------------------------
// Generic column-major matvec batch: out[t,b,e] = in[t,b,:].W[t,:,e] + bias
// K-split across KSP thread-groups (serial-K per thread = K/KSP), LDS reduce.
// grid = T * B_ * (N/ECH), block = ECH*KSP.
// ---------------------------------------------------------------------------
template<int K, int N, int B_, int ECH, int KSP, bool ADD_TT, bool GELU>
__global__ void k_mv(const float* __restrict__ in, const float* __restrict__ W,
                     const float* __restrict__ bias, const float* __restrict__ tt,
                     float* __restrict__ out) {
    __shared__ float red[KSP][ECH];
    constexpr int NCH = N / ECH;
    int blk = blockIdx.x;
    int t = blk / (B_ * NCH);
    int rem = blk % (B_ * NCH);
    int b = rem / NCH;
    int ec = rem % NCH;
    int tid = threadIdx.x;
    int le = tid % ECH;
    int kg = tid / ECH;
    int e = ec * ECH + le;
    const float* inr = in + ((size_t)t * B_ + b) * K;
    const float* wc = W + (size_t)t * K * N + e;
    float acc = 0.f;
    constexpr int KPT = K / KSP;
    int d0 = kg * KPT;
#pragma unroll 8
    for (int d = d0; d < d0 + KPT; ++d)
        acc += inr[d] * wc[(size_t)d * N];
    red[kg][le] = acc;
    __syncthreads();
    if (kg == 0) {
        float s = bias[t * N + e];
        if (ADD_TT) s += tt[t * N + e];
#pragma unroll
        for (int i = 0; i < KSP; ++i) s += red[i][le];
        if (GELU) s = 0.5f * s * (1.0f + erff(s * 0.70710678118654752f));
        out[((size_t)t * B_ + b) * N + e] = s;
    }
}

// ---------------------------------------------------------------------------
// K1b: kq[t,d] = SCALE * sum_e Wk[t,d,e] * q[t,e]   (row-contiguous matvec)
// grid 576 = T*192, one wave per d (4 waves/block)
// ---------------------------------------------------------------------------
__global__ void k_kq(const float* __restrict__ Wk, const float* __restrict__ q,
                     float* __restrict__ kq) {
    int t = blockIdx.x / 192;
    int d = (blockIdx.x % 192) * 4 + (threadIdx.x >> 6);
    int L = threadIdx.x & 63;
    const float4* wr = (const float4*)(Wk + (size_t)(t * DD + d) * DD);
    const float4* qr = (const float4*)(q + t * DD);
    float s = 0.f;
#pragma unroll
    for (int g = 0; g < 3; ++g) {
        float4 a = wr[g * 64 + L], b = qr[g * 64 + L];
        s += a.x * b.x + a.y * b.y + a.z * b.z + a.w * b.w;
    }
#pragma unroll
    for (int off = 32; off; off >>= 1) s += __shfl_xor(s, off);
    if (L == 0) kq[t * DD + d] = s * SCALE;
}

// ---------------------------------------------------------------------------
// K2 main stream: per x-row (skip masked!): s[t] = x_row . kq[t];
//   e = exp(s); l[t] += e; xa_acc[t] += e * x_row.
// grid 1024 = B*32 blocks, 256 threads (4 waves, 16 rows each).
// kq staged in LDS (union with reduce buffer) to keep VGPR <= 128.
// Outputs per-block partials: xap[bid][t*768+d], lp[bid][t].
// ---------------------------------------------------------------------------
__global__ __launch_bounds__(256, 4) void k_main(const float* __restrict__ x,
        const int* __restrict__ mask, const float* __restrict__ kq,
        float* __restrict__ xap, float* __restrict__ lp) {
    __shared__ float red[4][TT * DD];   // 36 KB; red[0..] doubles as kq stage
    __shared__ float redl[4][TT];
    int bid = blockIdx.x;
    int b = bid >> 5, c = bid & 31;
    int tid = threadIdx.x, w = tid >> 6, L = tid & 63;

    // stage kq (2304 floats) into LDS
    float* kqs = &red[0][0];
#pragma unroll
    for (int k2 = 0; k2 < 9; ++k2) kqs[tid + k2 * 256] = kq[tid + k2 * 256];
    __syncthreads();
    const float4* kq4 = (const float4*)kqs;

    float4 acc[TT][3] = {};
    float l[TT] = {0.f, 0.f, 0.f};
    const float* xb = x + (size_t)b * PP * DD;
    const int* mb = mask + b * PP;
    int p0 = c * ROWS + w * (ROWS / 4);

    for (int r = 0; r < ROWS / 4; ++r) {
        int p = p0 + r;
        if (mb[p]) continue;                       // masked rows contribute 0
        const float4* xr = (const float4*)(xb + (size_t)p * DD);
        float4 xv[3];
#pragma unroll
        for (int g = 0; g < 3; ++g) xv[g] = xr[g * 64 + L];
        float s[TT];
#pragma unroll
        for (int t = 0; t < TT; ++t) {
            float a = 0.f;
#pragma unroll
            for (int g = 0; g < 3; ++g) {
                float4 kf = kq4[t * 192 + g * 64 + L];
                a += xv[g].x * kf.x + xv[g].y * kf.y
                   + xv[g].z * kf.z + xv[g].w * kf.w;
            }
            s[t] = a;
        }
#pragma unroll
        for (int off = 32; off; off >>= 1) {
            s[0] += __shfl_xor(s[0], off);
            s[1] += __shfl_xor(s[1], off);
            s[2] += __shfl_xor(s[2], off);
        }
#pragma unroll
        for (int t = 0; t < TT; ++t) {
            float e = expf(s[t]);                  // scores are tiny; no max needed
            l[t] += e;
#pragma unroll
            for (int g = 0; g < 3; ++g) {
                acc[t][g].x += e * xv[g].x;
                acc[t][g].y += e * xv[g].y;
                acc[t][g].z += e * xv[g].z;
                acc[t][g].w += e * xv[g].w;
            }
        }
    }

    __syncthreads();   // everyone done reading kqs before overwrite
#pragma unroll
    for (int t = 0; t < TT; ++t)
#pragma unroll
        for (int g = 0; g < 3; ++g)
            *(float4*)&red[w][t * DD + g * 256 + 4 * L] = acc[t][g];
    if (L == 0) {
#pragma unroll
        for (int t = 0; t < TT; ++t) redl[w][t] = l[t];
    }
    __syncthreads();

    float* outp = xap + (size_t)bid * (TT * DD);
#pragma unroll
    for (int k = 0; k < 9; ++k) {
        int i = tid + k * 256;
        outp[i] = red[0][i] + red[1][i] + red[2][i] + red[3][i];
    }
    if (tid < TT)
        lp[bid * TT + tid] = redl[0][tid] + redl[1][tid] + redl[2][tid] + redl[3][tid];
}

// ---------------------------------------------------------------------------
// K3: combine chunk partials:  xa[t,b,d] = (sum_c xap) / (sum_c lp)
// grid 96 = T*B blocks, 256 threads
// ---------------------------------------------------------------------------
__global__ void k_comb(const float* __restrict__ xap, const float* __restrict__ lp,
                       float* __restrict__ xa) {
    int t = blockIdx.x >> 5, b = blockIdx.x & 31;
    int tid = threadIdx.x;
    float lsum = 0.f;
#pragma unroll
    for (int c = 0; c < CC; ++c) lsum += lp[(b * CC + c) * TT + t];
    float inv = 1.0f / lsum;
#pragma unroll
    for (int k = 0; k < 3; ++k) {
        int d = tid + k * 256;
        float s = 0.f;
#pragma unroll
        for (int c = 0; c < CC; ++c)
            s += xap[(size_t)(b * CC + c) * (TT * DD) + t * DD + d];
        xa[(t * BB + b) * DD + d] = s * inv;
    }
}

// ---------------------------------------------------------------------------
extern "C" void kernel_launch(void* const* d_in, const int* in_sizes, int n_in,
                              void* d_out, int out_size, void* d_ws, size_t ws_size,
                              hipStream_t stream) {
    const float* x    = (const float*)d_in[0];
    const int*   mask = (const int*)d_in[1];   // True = masked
    const float* tt   = (const float*)d_in[2];
    const float* Wq   = (const float*)d_in[3];
    const float* bq   = (const float*)d_in[4];
    const float* Wk   = (const float*)d_in[5];
    // d_in[6] = bk: unused — adds a per-(t) constant to scores, cancels in softmax
    const float* Wv   = (const float*)d_in[7];
    const float* bv   = (const float*)d_in[8];
    const float* Wo   = (const float*)d_in[9];
    const float* bo   = (const float*)d_in[10];
    const float* h1w  = (const float*)d_in[11];
    const float* h1b  = (const float*)d_in[12];
    const float* h2w  = (const float*)d_in[13];
    const float* h2b  = (const float*)d_in[14];
    float* out = (float*)d_out;

    // workspace layout (floats); total ~10.6 MB
    float* ws  = (float*)d_ws;
    float* q   = ws;                        // T*D         = 2304
    float* kq  = q + TT * DD;               // T*D         = 2304
    float* xap = kq + TT * DD;              // 1024*T*D    = 2,359,296
    float* lp  = xap + BB * CC * TT * DD;   // 1024*T      = 3072
    float* xa  = lp + BB * CC * TT;         // T*B*D       = 73728
    float* y   = xa + TT * BB * DD;         // T*B*D
    float* y2  = y + TT * BB * DD;          // T*B*D
    float* h   = y2 + TT * BB * DD;         // T*B*H       = 18432

    // q[t,e] = tt[t]. Wq[t,:,e] + bq  (B_=1, 16-way K-split, block 1024)
    hipLaunchKernelGGL((k_mv<DD, DD, 1, 64, 16, false, false>),
                       dim3(TT * 12), dim3(1024), 0, stream, tt, Wq, bq, nullptr, q);
    hipLaunchKernelGGL(k_kq,   dim3(576),  dim3(256), 0, stream, Wk, q, kq);
    hipLaunchKernelGGL(k_main, dim3(BB * CC), dim3(256), 0, stream, x, mask, kq, xap, lp);
    hipLaunchKernelGGL(k_comb, dim3(96),   dim3(256), 0, stream, xap, lp, xa);
    // y = xa @ Wv + bv
    hipLaunchKernelGGL((k_mv<DD, DD, BB, 64, 4, false, false>),
                       dim3(TT * BB * 12), dim3(256), 0, stream, xa, Wv, bv, nullptr, y);
    // y2 = y @ Wo + bo + tt
    hipLaunchKernelGGL((k_mv<DD, DD, BB, 64, 4, true, false>),
                       dim3(TT * BB * 12), dim3(256), 0, stream, y, Wo, bo, tt, y2);
    // h = gelu(y2 @ h1w + h1b)
    hipLaunchKernelGGL((k_mv<DD, HH, BB, 64, 4, false, true>),
                       dim3(TT * BB * 3), dim3(256), 0, stream, y2, h1w, h1b, nullptr, h);
    // out = h @ h2w + h2b
    hipLaunchKernelGGL((k_mv<HH, OO, BB, 128, 2, false, false>),
                       dim3(TT * BB * 1), dim3(256), 0, stream, h, h2w, h2b, nullptr, out);
}